// Round 5
// baseline (458.701 us; speedup 1.0000x reference)
//
#include <hip/hip_runtime.h>
#include <hip/hip_bf16.h>
#include <math.h>

typedef float floatx4 __attribute__((ext_vector_type(4)));
typedef __bf16 bf16x8 __attribute__((ext_vector_type(8)));
typedef unsigned short ushort_t;

__device__ __forceinline__ ushort_t f2bf(float f) {
    union { float f; unsigned int i; } v; v.f = f;
    unsigned int i = v.i;
    return (ushort_t)((i + 0x7FFFu + ((i >> 16) & 1u)) >> 16);  // RNE, inputs finite
}
__device__ __forceinline__ unsigned int pack2(float a, float b) {
    return (unsigned int)f2bf(a) | ((unsigned int)f2bf(b) << 16);
}
__device__ __forceinline__ floatx4 mfma16(bf16x8 a, bf16x8 b, floatx4 c) {
    return __builtin_amdgcn_mfma_f32_16x16x32_bf16(a, b, c, 0, 0, 0);
}
// async global->LDS, 16B/lane; g is PER-LANE address, lds base wave-uniform,
// lane i lands at lds_base + i*16 bytes
__device__ __forceinline__ void load_lds16(const ushort_t* g, ushort_t* l) {
    __builtin_amdgcn_global_load_lds(
        (const __attribute__((address_space(1))) unsigned int*)g,
        (__attribute__((address_space(3))) unsigned int*)l, 16, 0, 0);
}

#define G_SB   __builtin_amdgcn_sched_barrier(0)
#define G_BAR  __builtin_amdgcn_s_barrier()
#define WVM8   asm volatile("s_waitcnt vmcnt(8)" ::: "memory")
#define WVM0   asm volatile("s_waitcnt vmcnt(0)" ::: "memory")

// ---------------- Fused prep: activation fp32->bf16 convert (blocks 0..12799, 32B/thread),
// weight transpose+convert 64x64 tiles (blocks 12800..17919), lvT pad-zero (17920..18303).
__global__ __launch_bounds__(256) void k_prep(
    const float* __restrict__ q, const float* __restrict__ k,
    const float* __restrict__ v, const float* __restrict__ loc,
    const float* __restrict__ w0, const float* __restrict__ w1, const float* __restrict__ w2,
    const float* __restrict__ w3, const float* __restrict__ w4,
    ushort_t* qb, ushort_t* kb, ushort_t* vb, ushort_t* locb,
    ushort_t* t0, ushort_t* t1, ushort_t* t2, ushort_t* t3, ushort_t* t4,
    ushort_t* lvT) {
    __shared__ float tile[64][65];
    int blk = blockIdx.x;
    if (blk < 12800) {
        int z = blk / 3200, i = blk - z * 3200;
        const float* src = z == 0 ? q : z == 1 ? k : z == 2 ? v : loc;
        ushort_t* dst    = z == 0 ? qb : z == 1 ? kb : z == 2 ? vb : locb;
        size_t base = ((size_t)i * 256 + threadIdx.x) * 8;
        floatx4 f0 = *(const floatx4*)(src + base);
        floatx4 f1 = *(const floatx4*)(src + base + 4);
        uint4 o;
        o.x = pack2(f0[0], f0[1]); o.y = pack2(f0[2], f0[3]);
        o.z = pack2(f1[0], f1[1]); o.w = pack2(f1[2], f1[3]);
        *(uint4*)(dst + base) = o;
    } else if (blk < 17920) {
        int t = blk - 12800;
        int z = t / 1024, rr = t - z * 1024;
        const float* W = z == 0 ? w0 : z == 1 ? w1 : z == 2 ? w2 : z == 3 ? w3 : w4;
        ushort_t* T    = z == 0 ? t0 : z == 1 ? t1 : z == 2 ? t2 : z == 3 ? t3 : t4;
        int n0 = (rr & 31) * 64, k0 = (rr >> 5) * 64;
        int tx = threadIdx.x & 63, ty = threadIdx.x >> 6;   // ty 0..3
#pragma unroll
        for (int i = 0; i < 16; i++) {
            int row = ty + i * 4;
            tile[row][tx] = W[(size_t)(k0 + row) * 2048 + n0 + tx];
        }
        __syncthreads();
#pragma unroll
        for (int i = 0; i < 16; i++) {
            int row = ty + i * 4;
            T[(size_t)(n0 + row) * 2048 + k0 + tx] = f2bf(tile[tx][row]);
        }
    } else {
        // zero lvT pad cols t in [200,224): 16*2048 rows x 24, 8 ushorts/thread
        int t = blk - 17920;
        size_t e = ((size_t)t * 256 + threadIdx.x) * 8;   // < 786432
        int row = (int)(e / 24);
        int c = (int)(e - (size_t)row * 24);              // 0, 8, 16
        uint4 zz = {0, 0, 0, 0};
        *(uint4*)(lvT + (size_t)row * 224 + 200 + c) = zz;
    }
}

// ---------------- Batched projection GEMM — 128x128 tile (tail-free fine grid), BK=64,
// 64 KiB LDS double-buffer -> 2 blocks/CU, 4 waves (2M x 2N), counted vmcnt(8) (never 0
// in the loop), XOR-swizzled LDS (0 bank conflicts), XCD-aware swizzle.
// M = 3200 = 25x128 exactly. Grid 2000 = 25m x 16n x 5z = 8 XCDs x 250.
// z=0 -> lqp ; z=1 -> kcat[:, 0:2048] ; z=2 -> lvT DIRECT (transposed [b][n][t], pad
// cols pre-zeroed by k_prep) ; z=3 -> llocp ; z=4 -> kcat[:, 2048:4096]. kcat rows
// padded to 208 (pad rows never written; staged garbage is masked downstream).
__global__ __launch_bounds__(256, 2) void k_gemm(
    const ushort_t* A0, const ushort_t* A1, const ushort_t* A2, const ushort_t* A3, const ushort_t* A4,
    const ushort_t* W0, const ushort_t* W1, const ushort_t* W2, const ushort_t* W3, const ushort_t* W4,
    const float* B0, const float* B1, const float* B2, const float* B3, const float* B4,
    ushort_t* lqp, ushort_t* lvT, ushort_t* llocp, ushort_t* kcat) {
    // 2000 blocks = 8 XCDs x 250; bijective. Within an XCD: m-tiles fastest (25 per
    // n-panel) so the 0.5 MB B-panel stays L2-resident across 25 consecutive blocks.
    int bid = blockIdx.x;
    int tileid = (bid & 7) * 250 + (bid >> 3);
    int z = tileid / 400;              // 25 m x 16 n = 400 tiles per z
    int r = tileid - z * 400;
    int nt = r / 25;
    int mt = r - nt * 25;
    int m0 = mt * 128, n0 = nt * 128;

    const ushort_t* A  = z == 0 ? A0 : z == 1 ? A1 : z == 2 ? A2 : z == 3 ? A3 : A4;
    const ushort_t* Wt = z == 0 ? W0 : z == 1 ? W1 : z == 2 ? W2 : z == 3 ? W3 : W4;
    const float* bias  = z == 0 ? B0 : z == 1 ? B1 : z == 2 ? B2 : z == 3 ? B3 : B4;

    __shared__ ushort_t As[2][128 * 64];   // 16 KB each buffer
    __shared__ ushort_t Bs[2][128 * 64];

    int tid = threadIdx.x;
    int lane = tid & 63, w = tid >> 6;
    int quad = lane >> 4, col = lane & 15;
    int wr = w >> 1, wc = w & 1;

    // --- staging: per gload one wave covers 8 rows x 128 B. XOR swizzle (chunk ^= row&7)
    // applied on the GLOBAL source address; LDS written linearly.
    int sl = lane >> 3;
    int sc = ((lane & 7) ^ sl) * 8;        // element offset of swizzled 16B chunk
    const ushort_t* Ag[4]; const ushort_t* Bg[4]; int ldst[4];
#pragma unroll
    for (int u = 0; u < 4; u++) {
        int rowoff = u * 32 + w * 8;
        Ag[u] = A  + (size_t)(m0 + rowoff + sl) * 2048 + sc;
        Bg[u] = Wt + (size_t)(n0 + rowoff + sl) * 2048 + sc;
        ldst[u] = rowoff * 64;             // element offset inside one buffer
    }

#define STG(KT, BUF) do { int kk = (KT) * 64;              \
        load_lds16(Ag[0] + kk, As[BUF] + ldst[0]);         \
        load_lds16(Ag[1] + kk, As[BUF] + ldst[1]);         \
        load_lds16(Ag[2] + kk, As[BUF] + ldst[2]);         \
        load_lds16(Ag[3] + kk, As[BUF] + ldst[3]);         \
        load_lds16(Bg[0] + kk, Bs[BUF] + ldst[0]);         \
        load_lds16(Bg[1] + kk, Bs[BUF] + ldst[1]);         \
        load_lds16(Bg[2] + kk, Bs[BUF] + ldst[2]);         \
        load_lds16(Bg[3] + kk, Bs[BUF] + ldst[3]); } while (0)

    // --- ds_read offsets. frag(row, ks): elem row*64 + ((ks*4+quad)^(col&7))*8.
    int sw = col & 7;
    int ko0 = (quad ^ sw) * 8;
    int ko1 = ((4 | quad) ^ sw) * 8;
    int aro[4], bro[4];
#pragma unroll
    for (int mi = 0; mi < 4; mi++) aro[mi] = (wr * 64 + mi * 16 + col) * 64;
#pragma unroll
    for (int ni = 0; ni < 4; ni++) bro[ni] = (wc * 64 + ni * 16 + col) * 64;

    floatx4 acc[4][4] = {};

#define CMP(BUF) do {                                                     \
        bf16x8 af[4][2], bfr[4][2];                                       \
        _Pragma("unroll") for (int mi = 0; mi < 4; mi++) {                \
            af[mi][0] = *(const bf16x8*)&As[BUF][aro[mi] + ko0];          \
            af[mi][1] = *(const bf16x8*)&As[BUF][aro[mi] + ko1]; }        \
        _Pragma("unroll") for (int ni = 0; ni < 4; ni++) {                \
            bfr[ni][0] = *(const bf16x8*)&Bs[BUF][bro[ni] + ko0];         \
            bfr[ni][1] = *(const bf16x8*)&Bs[BUF][bro[ni] + ko1]; }       \
        __builtin_amdgcn_s_setprio(1);                                    \
        _Pragma("unroll") for (int mi = 0; mi < 4; mi++)                  \
        _Pragma("unroll") for (int ni = 0; ni < 4; ni++) {                \
            acc[mi][ni] = mfma16(af[mi][0], bfr[ni][0], acc[mi][ni]);     \
            acc[mi][ni] = mfma16(af[mi][1], bfr[ni][1], acc[mi][ni]); }   \
        __builtin_amdgcn_s_setprio(0); } while (0)

    STG(0, 0);
#pragma unroll 1
    for (int tt = 0; tt < 16; tt++) {
        int t0k = tt * 2;
        STG(t0k + 1, 1);
        WVM8;
        G_SB; G_BAR; G_SB;
        CMP(0);
        G_SB; G_BAR;
        STG((t0k + 2) & 31, 0);
        WVM8;
        G_SB; G_BAR; G_SB;
        CMP(1);
        G_SB; G_BAR;
    }
    WVM0;   // drain wrap-staging before LDS goes out of scope

    // --- epilogue: bias add, bf16 convert, store. M exact -> no row guard.
    float bvv[4];
#pragma unroll
    for (int ni = 0; ni < 4; ni++) bvv[ni] = bias[n0 + wc * 64 + ni * 16 + col];
    if (z == 2) {
        // direct transposed store: lvT[b][n][t], t stride 1 (2B scatter, 16 consecutive
        // t per n-column across the quad/r2 unroll -> L2 write-combined)
#pragma unroll
        for (int mi = 0; mi < 4; mi++) {
#pragma unroll
            for (int r2 = 0; r2 < 4; r2++) {
                int m = m0 + wr * 64 + mi * 16 + quad * 4 + r2;
                int bb = m / 200, rr = m - bb * 200;
                ushort_t* cb = lvT + (size_t)bb * 2048 * 224 + rr;
#pragma unroll
                for (int ni = 0; ni < 4; ni++) {
                    int n = n0 + wc * 64 + ni * 16 + col;
                    cb[(size_t)n * 224] = f2bf(acc[mi][ni][r2] + bvv[ni]);
                }
            }
        }
    } else {
        ushort_t* Cplain = z == 0 ? lqp : llocp;
        int kcoff = (z == 4) ? 2048 : 0;
        bool to_kcat = (z == 1 || z == 4);
#pragma unroll
        for (int mi = 0; mi < 4; mi++) {
#pragma unroll
            for (int r2 = 0; r2 < 4; r2++) {
                int m = m0 + wr * 64 + mi * 16 + quad * 4 + r2;
                ushort_t* crow;
                if (to_kcat) {
                    int bb = m / 200, rr = m - bb * 200;
                    crow = kcat + (size_t)(bb * 208 + rr) * 4096 + kcoff;
                } else {
                    crow = Cplain + (size_t)m * 2048;
                }
#pragma unroll
                for (int ni = 0; ni < 4; ni++) {
                    int n = n0 + wc * 64 + ni * 16 + col;
                    crow[n] = f2bf(acc[mi][ni][r2] + bvv[ni]);
                }
            }
        }
    }
#undef STG
#undef CMP
}

// ---------------- qcat[b][r][0:2048] = lq + param ; qcat[b][r][2048:] = lq + lloc
__global__ __launch_bounds__(256) void k_qprep(const ushort_t* __restrict__ lqp,
                                               const ushort_t* __restrict__ llocp,
                                               const float* __restrict__ param,
                                               ushort_t* __restrict__ qcat) {
    int m = blockIdx.x;           // 0..3199
    int b = m / 200, r = m - b * 200;
    int c = threadIdx.x * 8;
    bf16x8 ql = *(const bf16x8*)(lqp + (size_t)m * 2048 + c);
    bf16x8 ll = *(const bf16x8*)(llocp + (size_t)m * 2048 + c);
    floatx4 p0 = *(const floatx4*)(param + (size_t)m * 2048 + c);
    floatx4 p1 = *(const floatx4*)(param + (size_t)m * 2048 + c + 4);
    bf16x8 q1, q2;
#pragma unroll
    for (int j = 0; j < 4; j++) {
        q1[j]     = (__bf16)((float)ql[j] + p0[j]);
        q1[j + 4] = (__bf16)((float)ql[j + 4] + p1[j]);
        q2[j]     = (__bf16)((float)ql[j] + (float)ll[j]);
        q2[j + 4] = (__bf16)((float)ql[j + 4] + (float)ll[j + 4]);
    }
    ushort_t* dst = qcat + ((size_t)(b * 224 + r)) * 4096 + c;
    *(bf16x8*)dst = q1;
    *(bf16x8*)(dst + 2048) = q2;
}

// ---------------- Scores (4-way K-split): part[kc][b][row][key] fp32 partial.
// 448 blocks = 8 XCDs x 56 (bijective); qt-fastest within XCD so all 7 qt blocks of one
// (b,kc) share the kcat K-panel in L2. BK=64 double-buffer (64 KB LDS, 2 blocks/CU),
// source-side XOR swizzle, counted vmcnt(8), raw s_barrier. kcat row stride 208.
__global__ __launch_bounds__(256, 2) void k_scores(const ushort_t* __restrict__ qcat,
                                                   const ushort_t* __restrict__ kcat,
                                                   float* __restrict__ part) {
    int bid = blockIdx.x;
    int tile = (bid & 7) * 56 + (bid >> 3);
    int qt = tile % 7;           // 0..6   (32 q-rows)
    int t2 = tile / 7;
    int b  = t2 & 15;            // 0..15
    int kc = t2 >> 4;            // 0..3   (K-chunk of 1024)

    __shared__ ushort_t S[2][256 * 64];   // rows 0..31 = q, rows 32..255 = k; 32 KB/buf

    int tid = threadIdx.x;
    int lane = tid & 63, w = tid >> 6;
    int quad = lane >> 4, col = lane & 15;

    int sl = lane >> 3;
    int sc = ((lane & 7) ^ sl) * 8;       // pre-swizzled 16B chunk (element offset)

    const ushort_t* qbase = qcat + ((size_t)b * 224 + qt * 32) * 4096 + kc * 1024;
    const ushort_t* kbase = kcat + (size_t)b * 208 * 4096 + kc * 1024;

    const ushort_t* gsrc[8]; int ldst[8];
#pragma unroll
    for (int u = 0; u < 8; u++) {
        int row = u * 32 + w * 8;         // block row (0..255), 8-row slab per wave
        gsrc[u] = (u == 0) ? qbase + (size_t)(row + sl) * 4096 + sc
                           : kbase + (size_t)(row - 32 + sl) * 4096 + sc;
        ldst[u] = row * 64;
    }

#define SSTG(KT, BUF) do { int kk = (KT) * 64;                        \
        _Pragma("unroll") for (int u = 0; u < 8; u++)                 \
            load_lds16(gsrc[u] + kk, S[BUF] + ldst[u]); } while (0)

    int sw = col & 7;
    int ko0 = (quad ^ sw) * 8;
    int ko1 = ((4 | quad) ^ sw) * 8;

    floatx4 acc[2][4] = {};

#define SCMP(BUF) do {                                                    \
        bf16x8 af[2][2];                                                  \
        _Pragma("unroll") for (int mi = 0; mi < 2; mi++) {                \
            int ar = (mi * 16 + col) * 64;                                \
            af[mi][0] = *(const bf16x8*)&S[BUF][ar + ko0];                \
            af[mi][1] = *(const bf16x8*)&S[BUF][ar + ko1]; }              \
        __builtin_amdgcn_s_setprio(1);                                    \
        _Pragma("unroll") for (int fi = 0; fi < 4; fi++) {                \
            int f = w + fi * 4;                                           \
            if (f < 14) {                                                 \
                int br = (32 + f * 16 + col) * 64;                        \
                bf16x8 b0 = *(const bf16x8*)&S[BUF][br + ko0];            \
                bf16x8 b1 = *(const bf16x8*)&S[BUF][br + ko1];            \
                _Pragma("unroll") for (int mi = 0; mi < 2; mi++) {        \
                    acc[mi][fi] = mfma16(af[mi][0], b0, acc[mi][fi]);     \
                    acc[mi][fi] = mfma16(af[mi][1], b1, acc[mi][fi]); }   \
            } }                                                           \
        __builtin_amdgcn_s_setprio(0); } while (0)

    SSTG(0, 0);
#pragma unroll 1
    for (int tt = 0; tt < 8; tt++) {
        SSTG(2 * tt + 1, 1);
        WVM8; G_SB; G_BAR; G_SB;
        SCMP(0);
        G_SB; G_BAR;
        SSTG((2 * tt + 2) & 15, 0);
        WVM8; G_SB; G_BAR; G_SB;
        SCMP(1);
        G_SB; G_BAR;
    }
    WVM0;

    float* pbase = part + ((size_t)(kc * 16 + b) * 224 + qt * 32) * 224;
#pragma unroll
    for (int fi = 0; fi < 4; fi++) {
        int f = w + fi * 4;
        if (f < 14) {
#pragma unroll
            for (int mi = 0; mi < 2; mi++)
#pragma unroll
                for (int r = 0; r < 4; r++)
                    pbase[(mi * 16 + quad * 4 + r) * 224 + f * 16 + col] = acc[mi][fi][r];
        }
    }
#undef SSTG
#undef SCMP
}

// ---------------- softmax over 4 summed partials -> attn bf16 [b][200][224], cols>=200 zero
// grid 400 blocks x 256 thr; 8 rows/block, 32 threads/row, 7 cols/thread
__global__ __launch_bounds__(256) void k_softmax(const float* __restrict__ part,
                                                 ushort_t* __restrict__ attn) {
    int row = blockIdx.x * 8 + (threadIdx.x >> 5);  // 0..3199
    int b = row / 200, r = row - b * 200;
    int p = threadIdx.x & 31;
    const float* p0 = part + ((size_t)b * 224 + r) * 224;
    const size_t st = (size_t)16 * 224 * 224;
    const float scale = 0.022097086912079608f;  // 1/sqrt(2048)
    float ev[7];
    float mx = -1e30f;
#pragma unroll
    for (int j = 0; j < 7; j++) {
        int c = p * 7 + j;
        float v = (c < 200) ? (p0[c] + p0[c + st] + p0[c + 2 * st] + p0[c + 3 * st]) * scale
                            : -1e30f;
        ev[j] = v;
        mx = fmaxf(mx, v);
    }
#pragma unroll
    for (int m = 1; m < 32; m <<= 1) mx = fmaxf(mx, __shfl_xor(mx, m, 32));
    float s = 0.f;
#pragma unroll
    for (int j = 0; j < 7; j++) {
        float e = __expf(ev[j] - mx);
        ev[j] = e;
        s += e;
    }
#pragma unroll
    for (int m = 1; m < 32; m <<= 1) s += __shfl_xor(s, m, 32);
    float rs = 1.0f / s;
    ushort_t* arow = attn + (size_t)row * 224;
#pragma unroll
    for (int j = 0; j < 7; j++) {
        int c = p * 7 + j;
        arow[c] = (c < 200) ? f2bf(ev[j] * rs) : (ushort_t)0;
    }
}

// ---------------- out[b][m][n] = attn[b][m][:] @ lv (via lvT), fp32 out.
// 32 q-rows x 256 n-cols per block; grid (8 nt, 7 qt, 16 b) = 896 blocks, 4 waves
// (one 64-col slab each). lvT re-read 7x; no LDS (K=224 only).
__global__ __launch_bounds__(256) void k_pv(const ushort_t* __restrict__ attn,
                                            const ushort_t* __restrict__ lvT,
                                            float* __restrict__ out) {
    int nt = blockIdx.x;  // 0..7 (256 cols each)
    int qt = blockIdx.y;  // 0..6 (32 rows each)
    int b = blockIdx.z;
    int tid = threadIdx.x, lane = tid & 63, w = tid >> 6;
    int quad = lane >> 4, col = lane & 15;
    const ushort_t* arow[2];
#pragma unroll
    for (int mi = 0; mi < 2; mi++) {
        int aq = qt * 32 + mi * 16 + col; if (aq > 199) aq = 199;
        arow[mi] = attn + (size_t)(b * 200 + aq) * 224;
    }
    int nbase = nt * 256 + w * 64;
    const ushort_t* bp[4];
#pragma unroll
    for (int ni = 0; ni < 4; ni++)
        bp[ni] = lvT + ((size_t)b * 2048 + nbase + ni * 16 + col) * 224;
    floatx4 acc[2][4] = {};
#pragma unroll
    for (int k0 = 0; k0 < 224; k0 += 32) {
        int ko = k0 + quad * 8;
        bf16x8 av[2];
#pragma unroll
        for (int mi = 0; mi < 2; mi++) av[mi] = *(const bf16x8*)(arow[mi] + ko);
#pragma unroll
        for (int ni = 0; ni < 4; ni++) {
            bf16x8 bv = *(const bf16x8*)(bp[ni] + ko);
#pragma unroll
            for (int mi = 0; mi < 2; mi++) acc[mi][ni] = mfma16(av[mi], bv, acc[mi][ni]);
        }
    }
#pragma unroll
    for (int mi = 0; mi < 2; mi++) {
#pragma unroll
        for (int r = 0; r < 4; r++) {
            int m = qt * 32 + mi * 16 + quad * 4 + r;
            if (m < 200) {
#pragma unroll
                for (int ni = 0; ni < 4; ni++) {
                    int n = nbase + ni * 16 + col;
                    out[(size_t)(b * 200 + m) * 2048 + n] = acc[mi][ni][r];
                }
            }
        }
    }
}

extern "C" void kernel_launch(void* const* d_in, const int* in_sizes, int n_in,
                              void* d_out, int out_size, void* d_ws, size_t ws_size,
                              hipStream_t stream) {
    (void)in_sizes; (void)n_in; (void)out_size; (void)ws_size;
    const float* q    = (const float*)d_in[0];
    const float* k    = (const float*)d_in[1];
    const float* v    = (const float*)d_in[2];
    const float* loc  = (const float*)d_in[3];
    const float* Wq   = (const float*)d_in[4];
    const float* bq   = (const float*)d_in[5];
    const float* Wk   = (const float*)d_in[6];
    const float* bk   = (const float*)d_in[7];
    const float* Wv   = (const float*)d_in[8];
    const float* bv   = (const float*)d_in[9];
    const float* Wloc = (const float*)d_in[10];
    const float* bloc = (const float*)d_in[11];
    const float* Wlk  = (const float*)d_in[12];
    const float* blk  = (const float*)d_in[13];
    const float* param = (const float*)d_in[14];
    float* out = (float*)d_out;

    size_t off = 0;
    auto nxt = [&](size_t bytes) {
        void* p = (char*)d_ws + off;
        off += (bytes + 255) & ~(size_t)255;
        return p;
    };
    // total footprint 162.5 MB (within the previously-proven 163 MB envelope)
    ushort_t* wt[5];
    for (int i = 0; i < 5; i++) wt[i] = (ushort_t*)nxt(2048ull * 2048 * 2);
    ushort_t* qb    = (ushort_t*)nxt(3200ull * 2048 * 2);
    ushort_t* kb    = (ushort_t*)nxt(3200ull * 2048 * 2);
    ushort_t* vb    = (ushort_t*)nxt(3200ull * 2048 * 2);
    ushort_t* locb  = (ushort_t*)nxt(3200ull * 2048 * 2);
    ushort_t* lqp   = (ushort_t*)nxt(3200ull * 2048 * 2);
    ushort_t* llocp = (ushort_t*)nxt(3200ull * 2048 * 2);
    ushort_t* kcat  = (ushort_t*)nxt(16ull * 208 * 4096 * 2);   // rows padded to 208
    ushort_t* lvT   = (ushort_t*)nxt(16ull * 2048 * 224 * 2);   // written by k_gemm z=2
    // overlays (wt region 41.9 MB, dead after k_gemm):
    ushort_t* attn = wt[0];                               // 1.43 MB
    float*    part = (float*)(attn + 3200ull * 224);      // 12.85 MB (spills into wt[1], dead)
    ushort_t* qcat = qb;   // 29.4 MB into the 52.4 MB qb..locb region (dead after k_gemm)

    k_prep<<<dim3(18304), 256, 0, stream>>>(q, k, v, loc, Wq, Wk, Wv, Wloc, Wlk,
                                            qb, kb, vb, locb,
                                            wt[0], wt[1], wt[2], wt[3], wt[4], lvT);
    k_gemm<<<dim3(2000), 256, 0, stream>>>(qb, kb, vb, locb, locb,
                                           wt[0], wt[1], wt[2], wt[3], wt[4],
                                           bq, bk, bv, bloc, blk,
                                           lqp, lvT, llocp, kcat);
    k_qprep<<<dim3(3200), 256, 0, stream>>>(lqp, llocp, param, qcat);
    k_scores<<<dim3(448), 256, 0, stream>>>(qcat, kcat, part);
    k_softmax<<<dim3(400), 256, 0, stream>>>(part, attn);
    k_pv<<<dim3(8, 7, 16), 256, 0, stream>>>(attn, lvT, out);
}

// Round 6
// 432.883 us; speedup vs baseline: 1.0596x; 1.0596x over previous
//
#include <hip/hip_runtime.h>
#include <hip/hip_bf16.h>
#include <math.h>

typedef float floatx4 __attribute__((ext_vector_type(4)));
typedef __bf16 bf16x8 __attribute__((ext_vector_type(8)));
typedef unsigned short ushort_t;

__device__ __forceinline__ ushort_t f2bf(float f) {
    union { float f; unsigned int i; } v; v.f = f;
    unsigned int i = v.i;
    return (ushort_t)((i + 0x7FFFu + ((i >> 16) & 1u)) >> 16);  // RNE, inputs finite
}
__device__ __forceinline__ unsigned int pack2(float a, float b) {
    return (unsigned int)f2bf(a) | ((unsigned int)f2bf(b) << 16);
}
__device__ __forceinline__ floatx4 mfma16(bf16x8 a, bf16x8 b, floatx4 c) {
    return __builtin_amdgcn_mfma_f32_16x16x32_bf16(a, b, c, 0, 0, 0);
}
// async global->LDS, 16B/lane; g is PER-LANE address, lds base wave-uniform,
// lane i lands at lds_base + i*16 bytes
__device__ __forceinline__ void load_lds16(const ushort_t* g, ushort_t* l) {
    __builtin_amdgcn_global_load_lds(
        (const __attribute__((address_space(1))) unsigned int*)g,
        (__attribute__((address_space(3))) unsigned int*)l, 16, 0, 0);
}

#define G_SB   __builtin_amdgcn_sched_barrier(0)
#define G_BAR  __builtin_amdgcn_s_barrier()
#define WVM8   asm volatile("s_waitcnt vmcnt(8)" ::: "memory")
#define WVM0   asm volatile("s_waitcnt vmcnt(0)" ::: "memory")

// ---------------- Fused prep: activation fp32->bf16 convert (blocks 0..12799, 32B/thread),
// weight transpose+convert 64x64 tiles (blocks 12800..17919).
__global__ __launch_bounds__(256) void k_prep(
    const float* __restrict__ q, const float* __restrict__ k,
    const float* __restrict__ v, const float* __restrict__ loc,
    const float* __restrict__ w0, const float* __restrict__ w1, const float* __restrict__ w2,
    const float* __restrict__ w3, const float* __restrict__ w4,
    ushort_t* qb, ushort_t* kb, ushort_t* vb, ushort_t* locb,
    ushort_t* t0, ushort_t* t1, ushort_t* t2, ushort_t* t3, ushort_t* t4) {
    __shared__ float tile[64][65];
    int blk = blockIdx.x;
    if (blk < 12800) {
        int z = blk / 3200, i = blk - z * 3200;
        const float* src = z == 0 ? q : z == 1 ? k : z == 2 ? v : loc;
        ushort_t* dst    = z == 0 ? qb : z == 1 ? kb : z == 2 ? vb : locb;
        size_t base = ((size_t)i * 256 + threadIdx.x) * 8;
        floatx4 f0 = *(const floatx4*)(src + base);
        floatx4 f1 = *(const floatx4*)(src + base + 4);
        uint4 o;
        o.x = pack2(f0[0], f0[1]); o.y = pack2(f0[2], f0[3]);
        o.z = pack2(f1[0], f1[1]); o.w = pack2(f1[2], f1[3]);
        *(uint4*)(dst + base) = o;
    } else {
        int t = blk - 12800;
        int z = t / 1024, rr = t - z * 1024;
        const float* W = z == 0 ? w0 : z == 1 ? w1 : z == 2 ? w2 : z == 3 ? w3 : w4;
        ushort_t* T    = z == 0 ? t0 : z == 1 ? t1 : z == 2 ? t2 : z == 3 ? t3 : t4;
        int n0 = (rr & 31) * 64, k0 = (rr >> 5) * 64;
        int tx = threadIdx.x & 63, ty = threadIdx.x >> 6;   // ty 0..3
#pragma unroll
        for (int i = 0; i < 16; i++) {
            int row = ty + i * 4;
            tile[row][tx] = W[(size_t)(k0 + row) * 2048 + n0 + tx];
        }
        __syncthreads();
#pragma unroll
        for (int i = 0; i < 16; i++) {
            int row = ty + i * 4;
            T[(size_t)(n0 + row) * 2048 + k0 + tx] = f2bf(tile[tx][row]);
        }
    }
}

// ---------------- lv (3200x2048 bf16) -> lvT ([b][h][t] padded t->224, zeros)
__global__ void k_vtrans(const ushort_t* __restrict__ lv, ushort_t* __restrict__ lvT) {
    __shared__ ushort_t tile[32][33];
    int n0 = blockIdx.x * 32;
    int t0 = blockIdx.y * 32;
    int b = blockIdx.z;
    int tx = threadIdx.x & 31, ty = threadIdx.x >> 5;
#pragma unroll
    for (int i = 0; i < 4; i++) {
        int row = ty + i * 8;
        int tk = t0 + row;
        ushort_t vv = 0;
        if (tk < 200) vv = lv[(size_t)(b * 200 + tk) * 2048 + n0 + tx];
        tile[row][tx] = vv;
    }
    __syncthreads();
#pragma unroll
    for (int i = 0; i < 4; i++) {
        int row = ty + i * 8;
        lvT[((size_t)b * 2048 + n0 + row) * 224 + t0 + tx] = tile[tx][row];
    }
}

// ---------------- Batched projection GEMM — 128x128 tile (tail-free fine grid), BK=64,
// 64 KiB LDS double-buffer -> 2 blocks/CU, 4 waves (2M x 2N), counted vmcnt(8) (never 0
// in the loop), XOR-swizzled LDS (0 bank conflicts), XCD-aware swizzle.
// M = 3200 = 25x128 exactly. Grid 2000 = 25m x 16n x 5z = 8 XCDs x 250.
// z=0 -> lqp, z=1 -> kcat[:, 0:2048], z=2 -> lvp, z=3 -> llocp, z=4 -> kcat[:, 2048:4096]
// kcat rows padded to 208 (pad rows never written; staged garbage masked downstream).
__global__ __launch_bounds__(256, 2) void k_gemm(
    const ushort_t* A0, const ushort_t* A1, const ushort_t* A2, const ushort_t* A3, const ushort_t* A4,
    const ushort_t* W0, const ushort_t* W1, const ushort_t* W2, const ushort_t* W3, const ushort_t* W4,
    const float* B0, const float* B1, const float* B2, const float* B3, const float* B4,
    ushort_t* lqp, ushort_t* lvp, ushort_t* llocp, ushort_t* kcat) {
    // 2000 blocks = 8 XCDs x 250; bijective. Within an XCD: m-tiles fastest (25 per
    // n-panel) so the 0.5 MB B-panel stays L2-resident across 25 consecutive blocks.
    int bid = blockIdx.x;
    int tileid = (bid & 7) * 250 + (bid >> 3);
    int z = tileid / 400;              // 25 m x 16 n = 400 tiles per z
    int r = tileid - z * 400;
    int nt = r / 25;
    int mt = r - nt * 25;
    int m0 = mt * 128, n0 = nt * 128;

    const ushort_t* A  = z == 0 ? A0 : z == 1 ? A1 : z == 2 ? A2 : z == 3 ? A3 : A4;
    const ushort_t* Wt = z == 0 ? W0 : z == 1 ? W1 : z == 2 ? W2 : z == 3 ? W3 : W4;
    const float* bias  = z == 0 ? B0 : z == 1 ? B1 : z == 2 ? B2 : z == 3 ? B3 : B4;

    __shared__ ushort_t As[2][128 * 64];   // 16 KB each buffer
    __shared__ ushort_t Bs[2][128 * 64];

    int tid = threadIdx.x;
    int lane = tid & 63, w = tid >> 6;
    int quad = lane >> 4, col = lane & 15;
    int wr = w >> 1, wc = w & 1;

    // --- staging: per gload one wave covers 8 rows x 128 B. XOR swizzle (chunk ^= row&7)
    // applied on the GLOBAL source address; LDS written linearly.
    int sl = lane >> 3;
    int sc = ((lane & 7) ^ sl) * 8;        // element offset of swizzled 16B chunk
    const ushort_t* Ag[4]; const ushort_t* Bg[4]; int ldst[4];
#pragma unroll
    for (int u = 0; u < 4; u++) {
        int rowoff = u * 32 + w * 8;
        Ag[u] = A  + (size_t)(m0 + rowoff + sl) * 2048 + sc;
        Bg[u] = Wt + (size_t)(n0 + rowoff + sl) * 2048 + sc;
        ldst[u] = rowoff * 64;             // element offset inside one buffer
    }

#define STG(KT, BUF) do { int kk = (KT) * 64;              \
        load_lds16(Ag[0] + kk, As[BUF] + ldst[0]);         \
        load_lds16(Ag[1] + kk, As[BUF] + ldst[1]);         \
        load_lds16(Ag[2] + kk, As[BUF] + ldst[2]);         \
        load_lds16(Ag[3] + kk, As[BUF] + ldst[3]);         \
        load_lds16(Bg[0] + kk, Bs[BUF] + ldst[0]);         \
        load_lds16(Bg[1] + kk, Bs[BUF] + ldst[1]);         \
        load_lds16(Bg[2] + kk, Bs[BUF] + ldst[2]);         \
        load_lds16(Bg[3] + kk, Bs[BUF] + ldst[3]); } while (0)

    // --- ds_read offsets. frag(row, ks): elem row*64 + ((ks*4+quad)^(col&7))*8.
    int sw = col & 7;
    int ko0 = (quad ^ sw) * 8;
    int ko1 = ((4 | quad) ^ sw) * 8;
    int aro[4], bro[4];
#pragma unroll
    for (int mi = 0; mi < 4; mi++) aro[mi] = (wr * 64 + mi * 16 + col) * 64;
#pragma unroll
    for (int ni = 0; ni < 4; ni++) bro[ni] = (wc * 64 + ni * 16 + col) * 64;

    floatx4 acc[4][4] = {};

#define CMP(BUF) do {                                                     \
        bf16x8 af[4][2], bfr[4][2];                                       \
        _Pragma("unroll") for (int mi = 0; mi < 4; mi++) {                \
            af[mi][0] = *(const bf16x8*)&As[BUF][aro[mi] + ko0];          \
            af[mi][1] = *(const bf16x8*)&As[BUF][aro[mi] + ko1]; }        \
        _Pragma("unroll") for (int ni = 0; ni < 4; ni++) {                \
            bfr[ni][0] = *(const bf16x8*)&Bs[BUF][bro[ni] + ko0];         \
            bfr[ni][1] = *(const bf16x8*)&Bs[BUF][bro[ni] + ko1]; }       \
        __builtin_amdgcn_s_setprio(1);                                    \
        _Pragma("unroll") for (int mi = 0; mi < 4; mi++)                  \
        _Pragma("unroll") for (int ni = 0; ni < 4; ni++) {                \
            acc[mi][ni] = mfma16(af[mi][0], bfr[ni][0], acc[mi][ni]);     \
            acc[mi][ni] = mfma16(af[mi][1], bfr[ni][1], acc[mi][ni]); }   \
        __builtin_amdgcn_s_setprio(0); } while (0)

    STG(0, 0);
#pragma unroll 1
    for (int tt = 0; tt < 16; tt++) {
        int t0k = tt * 2;
        STG(t0k + 1, 1);
        WVM8;
        G_SB; G_BAR; G_SB;
        CMP(0);
        G_SB; G_BAR;
        STG((t0k + 2) & 31, 0);
        WVM8;
        G_SB; G_BAR; G_SB;
        CMP(1);
        G_SB; G_BAR;
    }
    WVM0;   // drain wrap-staging before LDS goes out of scope

    // --- epilogue: bias add, bf16 convert, store. M exact -> no row guard.
    ushort_t* Cplain = z == 0 ? lqp : z == 2 ? lvp : llocp;
    int kcoff = (z == 4) ? 2048 : 0;
    bool to_kcat = (z == 1 || z == 4);
    float bvv[4];
#pragma unroll
    for (int ni = 0; ni < 4; ni++) bvv[ni] = bias[n0 + wc * 64 + ni * 16 + col];
#pragma unroll
    for (int mi = 0; mi < 4; mi++) {
#pragma unroll
        for (int r2 = 0; r2 < 4; r2++) {
            int m = m0 + wr * 64 + mi * 16 + quad * 4 + r2;
            ushort_t* crow;
            if (to_kcat) {
                int bb = m / 200, rr = m - bb * 200;
                crow = kcat + (size_t)(bb * 208 + rr) * 4096 + kcoff;
            } else {
                crow = Cplain + (size_t)m * 2048;
            }
#pragma unroll
            for (int ni = 0; ni < 4; ni++) {
                int n = n0 + wc * 64 + ni * 16 + col;
                crow[n] = f2bf(acc[mi][ni][r2] + bvv[ni]);
            }
        }
    }
#undef STG
#undef CMP
}

// ---------------- qcat[b][r][0:2048] = lq + param ; qcat[b][r][2048:] = lq + lloc
__global__ __launch_bounds__(256) void k_qprep(const ushort_t* __restrict__ lqp,
                                               const ushort_t* __restrict__ llocp,
                                               const float* __restrict__ param,
                                               ushort_t* __restrict__ qcat) {
    int m = blockIdx.x;           // 0..3199
    int b = m / 200, r = m - b * 200;
    int c = threadIdx.x * 8;
    bf16x8 ql = *(const bf16x8*)(lqp + (size_t)m * 2048 + c);
    bf16x8 ll = *(const bf16x8*)(llocp + (size_t)m * 2048 + c);
    floatx4 p0 = *(const floatx4*)(param + (size_t)m * 2048 + c);
    floatx4 p1 = *(const floatx4*)(param + (size_t)m * 2048 + c + 4);
    bf16x8 q1, q2;
#pragma unroll
    for (int j = 0; j < 4; j++) {
        q1[j]     = (__bf16)((float)ql[j] + p0[j]);
        q1[j + 4] = (__bf16)((float)ql[j + 4] + p1[j]);
        q2[j]     = (__bf16)((float)ql[j] + (float)ll[j]);
        q2[j + 4] = (__bf16)((float)ql[j + 4] + (float)ll[j + 4]);
    }
    ushort_t* dst = qcat + ((size_t)(b * 224 + r)) * 4096 + c;
    *(bf16x8*)dst = q1;
    *(bf16x8*)(dst + 2048) = q2;
}

// ---------------- Scores (4-way K-split): part[kc][b][row][key] fp32 partial.
// 448 blocks = 8 XCDs x 56 (bijective); qt-fastest within XCD so all 7 qt blocks of one
// (b,kc) share the kcat K-panel in L2. BK=64 double-buffer (64 KB LDS, 2 blocks/CU),
// source-side XOR swizzle, counted vmcnt(8), raw s_barrier. kcat row stride 208.
__global__ __launch_bounds__(256, 2) void k_scores(const ushort_t* __restrict__ qcat,
                                                   const ushort_t* __restrict__ kcat,
                                                   float* __restrict__ part) {
    int bid = blockIdx.x;
    int tile = (bid & 7) * 56 + (bid >> 3);
    int qt = tile % 7;           // 0..6   (32 q-rows)
    int t2 = tile / 7;
    int b  = t2 & 15;            // 0..15
    int kc = t2 >> 4;            // 0..3   (K-chunk of 1024)

    __shared__ ushort_t S[2][256 * 64];   // rows 0..31 = q, rows 32..255 = k; 32 KB/buf

    int tid = threadIdx.x;
    int lane = tid & 63, w = tid >> 6;
    int quad = lane >> 4, col = lane & 15;

    int sl = lane >> 3;
    int sc = ((lane & 7) ^ sl) * 8;       // pre-swizzled 16B chunk (element offset)

    const ushort_t* qbase = qcat + ((size_t)b * 224 + qt * 32) * 4096 + kc * 1024;
    const ushort_t* kbase = kcat + (size_t)b * 208 * 4096 + kc * 1024;

    const ushort_t* gsrc[8]; int ldst[8];
#pragma unroll
    for (int u = 0; u < 8; u++) {
        int row = u * 32 + w * 8;         // block row (0..255), 8-row slab per wave
        gsrc[u] = (u == 0) ? qbase + (size_t)(row + sl) * 4096 + sc
                           : kbase + (size_t)(row - 32 + sl) * 4096 + sc;
        ldst[u] = row * 64;
    }

#define SSTG(KT, BUF) do { int kk = (KT) * 64;                        \
        _Pragma("unroll") for (int u = 0; u < 8; u++)                 \
            load_lds16(gsrc[u] + kk, S[BUF] + ldst[u]); } while (0)

    int sw = col & 7;
    int ko0 = (quad ^ sw) * 8;
    int ko1 = ((4 | quad) ^ sw) * 8;

    floatx4 acc[2][4] = {};

#define SCMP(BUF) do {                                                    \
        bf16x8 af[2][2];                                                  \
        _Pragma("unroll") for (int mi = 0; mi < 2; mi++) {                \
            int ar = (mi * 16 + col) * 64;                                \
            af[mi][0] = *(const bf16x8*)&S[BUF][ar + ko0];                \
            af[mi][1] = *(const bf16x8*)&S[BUF][ar + ko1]; }              \
        __builtin_amdgcn_s_setprio(1);                                    \
        _Pragma("unroll") for (int fi = 0; fi < 4; fi++) {                \
            int f = w + fi * 4;                                           \
            if (f < 14) {                                                 \
                int br = (32 + f * 16 + col) * 64;                        \
                bf16x8 b0 = *(const bf16x8*)&S[BUF][br + ko0];            \
                bf16x8 b1 = *(const bf16x8*)&S[BUF][br + ko1];            \
                _Pragma("unroll") for (int mi = 0; mi < 2; mi++) {        \
                    acc[mi][fi] = mfma16(af[mi][0], b0, acc[mi][fi]);     \
                    acc[mi][fi] = mfma16(af[mi][1], b1, acc[mi][fi]); }   \
            } }                                                           \
        __builtin_amdgcn_s_setprio(0); } while (0)

    SSTG(0, 0);
#pragma unroll 1
    for (int tt = 0; tt < 8; tt++) {
        SSTG(2 * tt + 1, 1);
        WVM8; G_SB; G_BAR; G_SB;
        SCMP(0);
        G_SB; G_BAR;
        SSTG((2 * tt + 2) & 15, 0);
        WVM8; G_SB; G_BAR; G_SB;
        SCMP(1);
        G_SB; G_BAR;
    }
    WVM0;

    float* pbase = part + ((size_t)(kc * 16 + b) * 224 + qt * 32) * 224;
#pragma unroll
    for (int fi = 0; fi < 4; fi++) {
        int f = w + fi * 4;
        if (f < 14) {
#pragma unroll
            for (int mi = 0; mi < 2; mi++)
#pragma unroll
                for (int r = 0; r < 4; r++)
                    pbase[(mi * 16 + quad * 4 + r) * 224 + f * 16 + col] = acc[mi][fi][r];
        }
    }
#undef SSTG
#undef SCMP
}

// ---------------- softmax over 4 summed partials -> attn bf16 [b][200][224], cols>=200 zero
// grid 400 blocks x 256 thr; 8 rows/block, 32 threads/row, 7 cols/thread
__global__ __launch_bounds__(256) void k_softmax(const float* __restrict__ part,
                                                 ushort_t* __restrict__ attn) {
    int row = blockIdx.x * 8 + (threadIdx.x >> 5);  // 0..3199
    int b = row / 200, r = row - b * 200;
    int p = threadIdx.x & 31;
    const float* p0 = part + ((size_t)b * 224 + r) * 224;
    const size_t st = (size_t)16 * 224 * 224;
    const float scale = 0.022097086912079608f;  // 1/sqrt(2048)
    float ev[7];
    float mx = -1e30f;
#pragma unroll
    for (int j = 0; j < 7; j++) {
        int c = p * 7 + j;
        float v = (c < 200) ? (p0[c] + p0[c + st] + p0[c + 2 * st] + p0[c + 3 * st]) * scale
                            : -1e30f;
        ev[j] = v;
        mx = fmaxf(mx, v);
    }
#pragma unroll
    for (int m = 1; m < 32; m <<= 1) mx = fmaxf(mx, __shfl_xor(mx, m, 32));
    float s = 0.f;
#pragma unroll
    for (int j = 0; j < 7; j++) {
        float e = __expf(ev[j] - mx);
        ev[j] = e;
        s += e;
    }
#pragma unroll
    for (int m = 1; m < 32; m <<= 1) s += __shfl_xor(s, m, 32);
    float rs = 1.0f / s;
    ushort_t* arow = attn + (size_t)row * 224;
#pragma unroll
    for (int j = 0; j < 7; j++) {
        int c = p * 7 + j;
        arow[c] = (c < 200) ? f2bf(ev[j] * rs) : (ushort_t)0;
    }
}

// ---------------- out[b][m][n] = attn[b][m][:] @ lv (via lvT), fp32 out.
// 32 q-rows x 256 n-cols per block; grid (8 nt, 7 qt, 16 b) = 896 blocks, 4 waves
// (one 64-col slab each). lvT re-read 7x; no LDS (K=224 only).
__global__ __launch_bounds__(256) void k_pv(const ushort_t* __restrict__ attn,
                                            const ushort_t* __restrict__ lvT,
                                            float* __restrict__ out) {
    int nt = blockIdx.x;  // 0..7 (256 cols each)
    int qt = blockIdx.y;  // 0..6 (32 rows each)
    int b = blockIdx.z;
    int tid = threadIdx.x, lane = tid & 63, w = tid >> 6;
    int quad = lane >> 4, col = lane & 15;
    const ushort_t* arow[2];
#pragma unroll
    for (int mi = 0; mi < 2; mi++) {
        int aq = qt * 32 + mi * 16 + col; if (aq > 199) aq = 199;
        arow[mi] = attn + (size_t)(b * 200 + aq) * 224;
    }
    int nbase = nt * 256 + w * 64;
    const ushort_t* bp[4];
#pragma unroll
    for (int ni = 0; ni < 4; ni++)
        bp[ni] = lvT + ((size_t)b * 2048 + nbase + ni * 16 + col) * 224;
    floatx4 acc[2][4] = {};
#pragma unroll
    for (int k0 = 0; k0 < 224; k0 += 32) {
        int ko = k0 + quad * 8;
        bf16x8 av[2];
#pragma unroll
        for (int mi = 0; mi < 2; mi++) av[mi] = *(const bf16x8*)(arow[mi] + ko);
#pragma unroll
        for (int ni = 0; ni < 4; ni++) {
            bf16x8 bv = *(const bf16x8*)(bp[ni] + ko);
#pragma unroll
            for (int mi = 0; mi < 2; mi++) acc[mi][ni] = mfma16(av[mi], bv, acc[mi][ni]);
        }
    }
#pragma unroll
    for (int mi = 0; mi < 2; mi++) {
#pragma unroll
        for (int r = 0; r < 4; r++) {
            int m = qt * 32 + mi * 16 + quad * 4 + r;
            if (m < 200) {
#pragma unroll
                for (int ni = 0; ni < 4; ni++) {
                    int n = nbase + ni * 16 + col;
                    out[(size_t)(b * 200 + m) * 2048 + n] = acc[mi][ni][r];
                }
            }
        }
    }
}

extern "C" void kernel_launch(void* const* d_in, const int* in_sizes, int n_in,
                              void* d_out, int out_size, void* d_ws, size_t ws_size,
                              hipStream_t stream) {
    (void)in_sizes; (void)n_in; (void)out_size; (void)ws_size;
    const float* q    = (const float*)d_in[0];
    const float* k    = (const float*)d_in[1];
    const float* v    = (const float*)d_in[2];
    const float* loc  = (const float*)d_in[3];
    const float* Wq   = (const float*)d_in[4];
    const float* bq   = (const float*)d_in[5];
    const float* Wk   = (const float*)d_in[6];
    const float* bk   = (const float*)d_in[7];
    const float* Wv   = (const float*)d_in[8];
    const float* bv   = (const float*)d_in[9];
    const float* Wloc = (const float*)d_in[10];
    const float* bloc = (const float*)d_in[11];
    const float* Wlk  = (const float*)d_in[12];
    const float* blk  = (const float*)d_in[13];
    const float* param = (const float*)d_in[14];
    float* out = (float*)d_out;

    size_t off = 0;
    auto nxt = [&](size_t bytes) {
        void* p = (char*)d_ws + off;
        off += (bytes + 255) & ~(size_t)255;
        return p;
    };
    ushort_t* wt[5];
    for (int i = 0; i < 5; i++) wt[i] = (ushort_t*)nxt(2048ull * 2048 * 2);
    ushort_t* qb    = (ushort_t*)nxt(3200ull * 2048 * 2);
    ushort_t* kb    = (ushort_t*)nxt(3200ull * 2048 * 2);
    ushort_t* vb    = (ushort_t*)nxt(3200ull * 2048 * 2);
    ushort_t* locb  = (ushort_t*)nxt(3200ull * 2048 * 2);
    ushort_t* lqp   = (ushort_t*)nxt(3200ull * 2048 * 2);
    ushort_t* llocp = (ushort_t*)nxt(3200ull * 2048 * 2);
    ushort_t* lvp   = (ushort_t*)nxt(3200ull * 2048 * 2);
    ushort_t* kcat  = (ushort_t*)nxt(16ull * 208 * 4096 * 2);   // rows padded to 208
    // overlays (wt region 41.9 MB, dead after k_gemm):
    ushort_t* lvT  = wt[0];                               // 0 .. 14.68 MB
    ushort_t* attn = wt[0] + 16ull * 2048 * 224;          // 14.68 .. 16.11 MB
    float*    part = (float*)(attn + 3200ull * 224);      // 16.11 .. 28.96 MB (wt region, dead)
    ushort_t* qcat = qb;   // 29.4 MB into the 52.4 MB qb..locb region (dead after k_gemm)

    k_prep<<<dim3(17920), 256, 0, stream>>>(q, k, v, loc, Wq, Wk, Wv, Wloc, Wlk,
                                            qb, kb, vb, locb,
                                            wt[0], wt[1], wt[2], wt[3], wt[4]);
    k_gemm<<<dim3(2000), 256, 0, stream>>>(qb, kb, vb, locb, locb,
                                           wt[0], wt[1], wt[2], wt[3], wt[4],
                                           bq, bk, bv, bloc, blk,
                                           lqp, lvp, llocp, kcat);
    k_qprep<<<dim3(3200), 256, 0, stream>>>(lqp, llocp, param, qcat);
    k_vtrans<<<dim3(64, 7, 16), 256, 0, stream>>>(lvp, lvT);
    k_scores<<<dim3(448), 256, 0, stream>>>(qcat, kcat, part);
    k_softmax<<<dim3(400), 256, 0, stream>>>(part, attn);
    k_pv<<<dim3(8, 7, 16), 256, 0, stream>>>(attn, lvT, out);
}